// Round 1
// 9884.457 us; speedup vs baseline: 1.7250x; 1.7250x over previous
//
#include <hip/hip_runtime.h>

// 2-layer tanh RNN, B=32, T=1024, H=1024. Squad-decomposed persistent pipeline.
//  - Recurrent squads: 2 layers x 2 bgroups x 16 WGs; each WG owns 16b x 64n,
//    holds ONLY Wh (hi/lo bf16) in VGPRs (256 VGPR), per-step: poll 4+1(+4)
//    flags -> fence -> 64KB h broadcast -> 96 MFMA/wave -> LDS reduce ->
//    + proj tile -> tanh -> write-through publish + per-WG flag.
//  - Projection squads: 2 layers x 2 bgroups x 16 WGs compute x@Wx+b (layer 0,
//    free-runs 32 steps ahead) and h0_t@Wx1+b (layer 1, one hop behind l0).
//    Off the recurrent critical path.
//  - Sync: per-producer flag words (no shared-counter RMW contention); each
//    consumer wave polls exactly the 4 producers covering its K-quarter.
#define BB 32
#define TT 1024
#define HH 1024
#define R0 32   // h0 ring depth
#define P0 32   // proj0 ring depth
#define P1 8    // proj1 ring depth
#define NP 16   // producers per group

typedef float f32x4 __attribute__((ext_vector_type(4)));
typedef short bf16x8 __attribute__((ext_vector_type(8)));
typedef unsigned uint4v __attribute__((ext_vector_type(4)));
typedef unsigned short u16;

__device__ __forceinline__ u16 f2bf(float f) {
  unsigned u = __builtin_bit_cast(unsigned, f);
  u += 0x7fffu + ((u >> 16) & 1u);   // RNE
  return (u16)(u >> 16);
}
__device__ __forceinline__ float bf2f(u16 h) {
  return __builtin_bit_cast(float, (unsigned)h << 16);
}
__device__ __forceinline__ bf16x8 packhi(f32x4 a, f32x4 b) {
  bf16x8 r;
  r[0] = (short)f2bf(a[0]); r[1] = (short)f2bf(a[1]);
  r[2] = (short)f2bf(a[2]); r[3] = (short)f2bf(a[3]);
  r[4] = (short)f2bf(b[0]); r[5] = (short)f2bf(b[1]);
  r[6] = (short)f2bf(b[2]); r[7] = (short)f2bf(b[3]);
  return r;
}
__device__ __forceinline__ bf16x8 packlo(f32x4 a, f32x4 b, bf16x8 hi) {
  bf16x8 r;
  r[0] = (short)f2bf(a[0] - bf2f((u16)hi[0]));
  r[1] = (short)f2bf(a[1] - bf2f((u16)hi[1]));
  r[2] = (short)f2bf(a[2] - bf2f((u16)hi[2]));
  r[3] = (short)f2bf(a[3] - bf2f((u16)hi[3]));
  r[4] = (short)f2bf(b[0] - bf2f((u16)hi[4]));
  r[5] = (short)f2bf(b[1] - bf2f((u16)hi[5]));
  r[6] = (short)f2bf(b[2] - bf2f((u16)hi[6]));
  r[7] = (short)f2bf(b[3] - bf2f((u16)hi[7]));
  return r;
}
__device__ __forceinline__ bf16x8 mergelo(uint4v q0, uint4v q1) {  // hi-bf16 plane
  uint4v r;
  r.x = __builtin_amdgcn_perm(q0.y, q0.x, 0x05040100u);
  r.y = __builtin_amdgcn_perm(q0.w, q0.z, 0x05040100u);
  r.z = __builtin_amdgcn_perm(q1.y, q1.x, 0x05040100u);
  r.w = __builtin_amdgcn_perm(q1.w, q1.z, 0x05040100u);
  return __builtin_bit_cast(bf16x8, r);
}
__device__ __forceinline__ bf16x8 mergehi(uint4v q0, uint4v q1) {  // lo-bf16 plane
  uint4v r;
  r.x = __builtin_amdgcn_perm(q0.y, q0.x, 0x07060302u);
  r.y = __builtin_amdgcn_perm(q0.w, q0.z, 0x07060302u);
  r.z = __builtin_amdgcn_perm(q1.y, q1.x, 0x07060302u);
  r.w = __builtin_amdgcn_perm(q1.w, q1.z, 0x07060302u);
  return __builtin_bit_cast(bf16x8, r);
}
__device__ __forceinline__ void spin(const unsigned* p, unsigned tgt) {
  while (__hip_atomic_load(p, __ATOMIC_RELAXED, __HIP_MEMORY_SCOPE_AGENT) < tgt)
    __builtin_amdgcn_s_sleep(1);
}
#define MFMA __builtin_amdgcn_mfma_f32_16x16x32_bf16

__global__ __launch_bounds__(256, 1) void rnn_fused(
    const float* __restrict__ x, const float* __restrict__ Wx,
    const float* __restrict__ Wh, const float* __restrict__ bx,
    const float* __restrict__ bh, float* __restrict__ out,
    unsigned* __restrict__ ring0,  // [R0][BB][HH] u32 (hi|lo<<16)  h0
    unsigned* __restrict__ h1r,    // [2][BB][HH]  u32               h1
    float* __restrict__ pj0,       // [P0][BB][HH] f32  x@Wx0+b0
    float* __restrict__ pj1,       // [P1][BB][HH] f32  h0@Wx1+b1
    unsigned* __restrict__ flg)    // [8][TT][NP]  per-producer flags
{
  __shared__ float red[4][16 * 68];   // padded: write 2-way, read ~4-way max
  const int tid  = threadIdx.x;
  const int wg   = blockIdx.x;
  const int role  = wg >> 6;        // 0 = recurrent, 1 = projection
  const int layer = (wg >> 5) & 1;
  const int bg    = (wg >> 4) & 1;
  const int idx   = wg & 15;
  const int n0    = idx << 6;       // 64 output cols per WG
  const int b0    = bg << 4;        // 16 batch rows per group
  const int lane  = tid & 63;
  const int wv    = tid >> 6;       // wave = K-quarter (256 K)
  const int am    = lane & 15;
  const int aq    = lane >> 4;
  const int fragoff = (wv << 8) + (aq << 3);
  const int rowE = tid >> 4;        // epilogue: batch row
  const int cb   = tid & 15;        // epilogue: col base; owns cols cb+16k

  // ---- one-time: weight B-fragments into VGPRs (hi/lo), 4 n-tiles ----
  // rec squads hold Wh only; proj squads hold Wx only.
  const float* WM = (role == 0 ? Wh : Wx) + (size_t)layer * HH * HH;
  bf16x8 wHi[4][8], wLo[4][8];
  #pragma unroll
  for (int j = 0; j < 4; ++j) {
    const float* p = WM + (size_t)(n0 + (j << 4) + am) * HH + fragoff;
    #pragma unroll
    for (int ss = 0; ss < 8; ++ss) {
      f32x4 a = *(const f32x4*)(p + (ss << 5));
      f32x4 b = *(const f32x4*)(p + (ss << 5) + 4);
      wHi[j][ss] = packhi(a, b);
      wLo[j][ss] = packlo(a, b, wHi[j][ss]);
    }
  }
  const f32x4 z4 = {0.f, 0.f, 0.f, 0.f};

  if (role == 0) {
    // ========================= recurrent squad =========================
    const int gOwn = layer * 2 + bg;       // own h flags
    const int gPrj = 4 + layer * 2 + bg;   // my proj squad
    const int gBP  = 6 + bg;               // proj1(bg) — ring0 consumer (l0 only)
    for (int t = 0; t < TT; ++t) {
      // one fused divergent poll: lanes 0-3 own K-quarter producers,
      // lane 4 proj tile, lanes 8-11 ring0 backpressure (layer 0).
      const unsigned* pa = nullptr;
      if (lane < 4) {
        if (t >= 1) pa = flg + ((size_t)gOwn * TT + (t - 1)) * NP + (wv << 2) + lane;
      } else if (lane == 4) {
        pa = flg + ((size_t)gPrj * TT + t) * NP + idx;
      } else if (lane >= 8 && lane < 12 && layer == 0 && t >= R0) {
        pa = flg + ((size_t)gBP * TT + (t - R0)) * NP + (wv << 2) + (lane - 8);
      }
      if (pa) spin(pa, 1);
      __builtin_amdgcn_fence(__ATOMIC_ACQUIRE, "agent");

      const unsigned* hp = (layer == 0
            ? ring0 + (size_t)((t - 1) & (R0 - 1)) * (BB * HH)
            : h1r  + (size_t)((t - 1) & 1) * (BB * HH))
          + (b0 + am) * HH + fragoff;

      f32x4 accA[4] = {z4, z4, z4, z4};
      f32x4 accB[4] = {z4, z4, z4, z4};
      f32x4 accC[4] = {z4, z4, z4, z4};
      #pragma unroll
      for (int ss = 0; ss < 8; ++ss) {
        uint4v q0 = *(const uint4v*)(hp + (ss << 5));
        uint4v q1 = *(const uint4v*)(hp + (ss << 5) + 4);
        bf16x8 aH = mergelo(q0, q1);
        bf16x8 aL = mergehi(q0, q1);
        #pragma unroll
        for (int j = 0; j < 4; ++j) {
          accA[j] = MFMA(aH, wHi[j][ss], accA[j], 0, 0, 0);
          accB[j] = MFMA(aH, wLo[j][ss], accB[j], 0, 0, 0);
          accC[j] = MFMA(aL, wHi[j][ss], accC[j], 0, 0, 0);
        }
      }

      // cross-wave K-reduce
      #pragma unroll
      for (int j = 0; j < 4; ++j) {
        f32x4 s = (accA[j] + accB[j]) + accC[j];
        #pragma unroll
        for (int i = 0; i < 4; ++i)
          red[wv][((aq << 2) + i) * 68 + (j << 4) + am] = s[i];
      }
      __syncthreads();

      const float* pjrow = (layer == 0
            ? pj0 + (size_t)(t & (P0 - 1)) * (BB * HH)
            : pj1 + (size_t)(t & (P1 - 1)) * (BB * HH))
          + (b0 + rowE) * HH + n0;
      unsigned* dst = (layer == 0
            ? ring0 + (size_t)(t & (R0 - 1)) * (BB * HH)
            : h1r  + (size_t)(t & 1) * (BB * HH))
          + (b0 + rowE) * HH + n0;

      float hv[4]; unsigned pk[4];
      #pragma unroll
      for (int k = 0; k < 4; ++k) {
        const int c = cb + (k << 4);
        float v = red[0][rowE * 68 + c] + red[1][rowE * 68 + c]
                + red[2][rowE * 68 + c] + red[3][rowE * 68 + c] + pjrow[c];
        hv[k] = tanhf(v);
        unsigned p0 = (unsigned)f2bf(hv[k]);
        p0 |= (unsigned)f2bf(hv[k] - bf2f((u16)p0)) << 16;
        pk[k] = p0;
      }
      #pragma unroll
      for (int k = 0; k < 4; ++k)
        __hip_atomic_store(&dst[cb + (k << 4)], pk[k],
                           __ATOMIC_RELAXED, __HIP_MEMORY_SCOPE_AGENT);
      __syncthreads();   // drains every wave's vmcnt -> stores LLC-visible
      if (tid == 0)
        __hip_atomic_store(flg + ((size_t)gOwn * TT + t) * NP + idx, 1u,
                           __ATOMIC_RELEASE, __HIP_MEMORY_SCOPE_AGENT);

      // off-critical-path work after publishing
      if (layer == 1) {
        #pragma unroll
        for (int k = 0; k < 4; ++k)
          out[(size_t)(b0 + rowE) * (TT * HH) + (size_t)t * HH + n0 + cb + (k << 4)] = hv[k];
      }
      if (t == TT - 1) {
        #pragma unroll
        for (int k = 0; k < 4; ++k)
          out[(size_t)BB * TT * HH + (size_t)layer * (BB * HH)
              + (b0 + rowE) * HH + n0 + cb + (k << 4)] = hv[k];
      }
    }
  } else {
    // ========================= projection squad =========================
    const int gOut = 4 + layer * 2 + bg;
    const int gIn  = bg;                       // rec-l0 flags (layer-1 input)
    const int gBPf = (layer == 0) ? bg : (2 + bg);   // my consumer squad
    const int Pd   = (layer == 0) ? P0 : P1;
    float* pring   = (layer == 0) ? pj0 : pj1;
    float bias[4];
    #pragma unroll
    for (int k = 0; k < 4; ++k)
      bias[k] = bx[layer * HH + n0 + cb + (k << 4)]
              + bh[layer * HH + n0 + cb + (k << 4)];

    for (int t = 0; t < TT; ++t) {
      const unsigned* pa = nullptr;
      if (lane < 4) {
        if (layer == 1) pa = flg + ((size_t)gIn * TT + t) * NP + (wv << 2) + lane;
      } else if (lane >= 8 && lane < 12 && t >= Pd) {
        pa = flg + ((size_t)gBPf * TT + (t - Pd)) * NP + (wv << 2) + (lane - 8);
      }
      if (pa) spin(pa, 1);
      if (layer == 1) __builtin_amdgcn_fence(__ATOMIC_ACQUIRE, "agent");
      // layer 0 reads only x (never written) + monotonic flags: no fence.

      f32x4 accA[4] = {z4, z4, z4, z4};
      f32x4 accB[4] = {z4, z4, z4, z4};
      f32x4 accC[4] = {z4, z4, z4, z4};
      if (layer == 0) {
        const float* xp = x + (size_t)(b0 + am) * (TT * HH) + (size_t)t * HH + fragoff;
        #pragma unroll
        for (int ss = 0; ss < 8; ++ss) {
          f32x4 a = *(const f32x4*)(xp + (ss << 5));
          f32x4 b = *(const f32x4*)(xp + (ss << 5) + 4);
          bf16x8 xh = packhi(a, b);
          bf16x8 xl = packlo(a, b, xh);
          #pragma unroll
          for (int j = 0; j < 4; ++j) {
            accA[j] = MFMA(xh, wHi[j][ss], accA[j], 0, 0, 0);
            accB[j] = MFMA(xh, wLo[j][ss], accB[j], 0, 0, 0);
            accC[j] = MFMA(xl, wHi[j][ss], accC[j], 0, 0, 0);
          }
        }
      } else {
        const unsigned* gp = ring0 + (size_t)(t & (R0 - 1)) * (BB * HH)
                           + (b0 + am) * HH + fragoff;
        #pragma unroll
        for (int ss = 0; ss < 8; ++ss) {
          uint4v q0 = *(const uint4v*)(gp + (ss << 5));
          uint4v q1 = *(const uint4v*)(gp + (ss << 5) + 4);
          bf16x8 gH = mergelo(q0, q1);
          bf16x8 gL = mergehi(q0, q1);
          #pragma unroll
          for (int j = 0; j < 4; ++j) {
            accA[j] = MFMA(gH, wHi[j][ss], accA[j], 0, 0, 0);
            accB[j] = MFMA(gH, wLo[j][ss], accB[j], 0, 0, 0);
            accC[j] = MFMA(gL, wHi[j][ss], accC[j], 0, 0, 0);
          }
        }
      }

      #pragma unroll
      for (int j = 0; j < 4; ++j) {
        f32x4 s = (accA[j] + accB[j]) + accC[j];
        #pragma unroll
        for (int i = 0; i < 4; ++i)
          red[wv][((aq << 2) + i) * 68 + (j << 4) + am] = s[i];
      }
      __syncthreads();

      float* dst = pring + (size_t)(t & (Pd - 1)) * (BB * HH)
                 + (b0 + rowE) * HH + n0;
      #pragma unroll
      for (int k = 0; k < 4; ++k) {
        const int c = cb + (k << 4);
        float v = red[0][rowE * 68 + c] + red[1][rowE * 68 + c]
                + red[2][rowE * 68 + c] + red[3][rowE * 68 + c] + bias[k];
        __hip_atomic_store(&dst[c], v, __ATOMIC_RELAXED, __HIP_MEMORY_SCOPE_AGENT);
      }
      __syncthreads();
      if (tid == 0)
        __hip_atomic_store(flg + ((size_t)gOut * TT + t) * NP + idx, 1u,
                           __ATOMIC_RELEASE, __HIP_MEMORY_SCOPE_AGENT);
    }
  }
}

// Zero what is read before first write (harness poisons ws with 0xAA):
// ring0 slot R0-1 (h0_{-1}=0), h1r slot 1 (h1_{-1}=0), all flags.
__global__ void prep(unsigned* ring0, unsigned* h1r, unsigned* flg) {
  int i = blockIdx.x * 256 + threadIdx.x;
  if (i < BB * HH) {
    ring0[(size_t)(R0 - 1) * (BB * HH) + i] = 0;
    h1r[(size_t)(BB * HH) + i] = 0;
  }
  if (i < 8 * TT * NP) flg[i] = 0;
}

extern "C" void kernel_launch(void* const* d_in, const int* in_sizes, int n_in,
                              void* d_out, int out_size, void* d_ws, size_t ws_size,
                              hipStream_t stream) {
  const float* x  = (const float*)d_in[0];
  const float* Wx = (const float*)d_in[1];
  const float* Wh = (const float*)d_in[2];
  const float* bx = (const float*)d_in[3];
  const float* bh = (const float*)d_in[4];
  float* out = (float*)d_out;

  char* ws = (char*)d_ws;
  unsigned* ring0 = (unsigned*)ws;                                   // 4 MiB
  size_t o = (size_t)R0 * BB * HH * sizeof(unsigned);
  unsigned* h1r = (unsigned*)(ws + o);                               // 256 KiB
  o += (size_t)2 * BB * HH * sizeof(unsigned);
  float* pj0 = (float*)(ws + o);                                     // 4 MiB
  o += (size_t)P0 * BB * HH * sizeof(float);
  float* pj1 = (float*)(ws + o);                                     // 1 MiB
  o += (size_t)P1 * BB * HH * sizeof(float);
  unsigned* flg = (unsigned*)(ws + o);                               // 512 KiB

  prep<<<512, 256, 0, stream>>>(ring0, h1r, flg);
  rnn_fused<<<128, 256, 0, stream>>>(x, Wx, Wh, bx, bh, out,
                                     ring0, h1r, pj0, pj1, flg);
}